// Round 19
// baseline (231.163 us; speedup 1.0000x reference)
//
#include <hip/hip_runtime.h>
#include <hip/hip_bf16.h>

#define SEQ 2048
#define BATCH 2
#define NH 16
#define DM 1024
#define DEPTH 64
#define MROWS (BATCH * SEQ)   // 4096

typedef __attribute__((ext_vector_type(8))) short bf16x8;
typedef __attribute__((ext_vector_type(4))) float f32x4;

__device__ __forceinline__ float b2f(ushort u) {
    union { uint i; float f; } v; v.i = ((uint)u) << 16; return v.f;
}
__device__ __forceinline__ ushort f2b(float f) {
    __hip_bfloat16 h = __float2bfloat16(f);
    return *reinterpret_cast<ushort*>(&h);
}

__device__ __forceinline__ void gload_lds16(const void* g, void* l) {
    __builtin_amdgcn_global_load_lds((const __attribute__((address_space(1))) void*)g,
                                     (__attribute__((address_space(3))) void*)l, 16, 0, 0);
}

// ---------------- fp32 -> bf16 elementwise ----------------
__global__ __launch_bounds__(256) void convert_f32_bf16(const float* __restrict__ in,
                                                        ushort* __restrict__ outp, int n4) {
    int i = blockIdx.x * 256 + threadIdx.x;
    if (i < n4) {
        const float4 v = ((const float4*)in)[i];
        ushort4 o;
        o.x = f2b(v.x); o.y = f2b(v.y); o.z = f2b(v.z); o.w = f2b(v.w);
        ((ushort4*)outp)[i] = o;
    }
}

// ---------------- 4x fused: fp32 W[K][N] -> bf16 Wt[N][K], z selects weight ----------------
__global__ __launch_bounds__(256) void transpose_convert4(const float* __restrict__ w0,
                                                          const float* __restrict__ w1,
                                                          const float* __restrict__ w2,
                                                          const float* __restrict__ w3,
                                                          ushort* __restrict__ WtBase) {
    __shared__ float tile[32][33];
    const int z = blockIdx.z;
    const float* W = (z == 0) ? w0 : (z == 1) ? w1 : (z == 2) ? w2 : w3;
    ushort* Wt = WtBase + (size_t)z * DM * DM;
    const int bx = blockIdx.x * 32;  // n base
    const int by = blockIdx.y * 32;  // k base
    const int tx = threadIdx.x & 31, ty = threadIdx.x >> 5;
#pragma unroll
    for (int i = 0; i < 32; i += 8)
        tile[ty + i][tx] = W[(size_t)(by + ty + i) * DM + bx + tx];
    __syncthreads();
#pragma unroll
    for (int i = 0; i < 32; i += 8)
        Wt[(size_t)(bx + ty + i) * DM + by + tx] = f2b(tile[tx][ty + i]);
}

// ---------------- fused QKV GEMM: [4096,1024] @ [1024,3072] + bias -> bf16 ----------------
// Swapped-operand MFMA: mfma(bfr, af) => C col(lane&15) = x-row (seq), C row = W-col (d).
// Lane holds 4 CONSECUTIVE d's per frag -> epilogue is 16 x ushort4 stores (was 64 scalar).
// Q bank (bank==0) pre-scaled by 1/sqrt(DEPTH)=0.125 so attn skips the logit scale.
__global__ __launch_bounds__(256) void gemm_qkv_mfma(const ushort* __restrict__ A,
                                                     const ushort* __restrict__ WtAll,
                                                     const float* __restrict__ bq,
                                                     const float* __restrict__ bk,
                                                     const float* __restrict__ bv,
                                                     ushort* __restrict__ OutBase) {
    __shared__ __align__(16) ushort As[128 * 32];
    __shared__ __align__(16) ushort Bs[128 * 32];

    const int t    = threadIdx.x;
    const int lane = t & 63;
    const int w    = t >> 6;
    const int wr   = w >> 1, wc = w & 1;
    const int row0 = blockIdx.y * 128;
    const int col0 = blockIdx.x * 128;           // 0..2944
    const int bank = col0 >> 10;                 // 0,1,2
    const float* bias = (bank == 0) ? bq : (bank == 1) ? bk : bv;
    const float scale = (bank == 0) ? 0.125f : 1.0f;
    const int ccol0 = col0 & 1023;
    ushort* Cout = OutBase + (size_t)bank * MROWS * DM;

    f32x4 acc[4][4];
#pragma unroll
    for (int mi = 0; mi < 4; ++mi)
#pragma unroll
        for (int ni = 0; ni < 4; ++ni) acc[mi][ni] = (f32x4){0.f, 0.f, 0.f, 0.f};

    const int sr = t >> 2;
    const int sc = (t & 3) * 8;

    for (int k0 = 0; k0 < DM; k0 += 32) {
        gload_lds16(&A[(size_t)(row0 + sr) * DM + k0 + sc],          &As[w * 512]);
        gload_lds16(&A[(size_t)(row0 + 64 + sr) * DM + k0 + sc],     &As[2048 + w * 512]);
        gload_lds16(&WtAll[(size_t)(col0 + sr) * DM + k0 + sc],      &Bs[w * 512]);
        gload_lds16(&WtAll[(size_t)(col0 + 64 + sr) * DM + k0 + sc], &Bs[2048 + w * 512]);
        __syncthreads();

        bf16x8 af[4], bfr[4];
#pragma unroll
        for (int mi = 0; mi < 4; ++mi)
            af[mi] = *(const bf16x8*)&As[(wr * 64 + mi * 16 + (lane & 15)) * 32 + (lane >> 4) * 8];
#pragma unroll
        for (int ni = 0; ni < 4; ++ni)
            bfr[ni] = *(const bf16x8*)&Bs[(wc * 64 + ni * 16 + (lane & 15)) * 32 + (lane >> 4) * 8];
#pragma unroll
        for (int mi = 0; mi < 4; ++mi)
#pragma unroll
            for (int ni = 0; ni < 4; ++ni)
                acc[mi][ni] = __builtin_amdgcn_mfma_f32_16x16x32_bf16(bfr[ni], af[mi], acc[mi][ni], 0, 0, 0);
        __syncthreads();
    }

#pragma unroll
    for (int mi = 0; mi < 4; ++mi) {
        const int seq = row0 + wr * 64 + mi * 16 + (lane & 15);
#pragma unroll
        for (int ni = 0; ni < 4; ++ni) {
            const int dbase = ccol0 + wc * 64 + ni * 16 + (lane >> 4) * 4;
            const float4 b4 = *(const float4*)&bias[dbase];
            ushort4 o;
            o.x = f2b((acc[mi][ni][0] + b4.x) * scale);
            o.y = f2b((acc[mi][ni][1] + b4.y) * scale);
            o.z = f2b((acc[mi][ni][2] + b4.z) * scale);
            o.w = f2b((acc[mi][ni][3] + b4.w) * scale);
            *(ushort4*)&Cout[(size_t)seq * DM + dbase] = o;
        }
    }
}

// ---------------- bf16 MFMA GEMM: C = A @ Wt^T + bias, fp32 out (swapped-operand) ----------
__global__ __launch_bounds__(256) void gemm_mfma_f32(const ushort* __restrict__ A,
                                                     const ushort* __restrict__ Wt,
                                                     const float* __restrict__ bias,
                                                     float* __restrict__ Cout) {
    __shared__ __align__(16) ushort As[128 * 32];
    __shared__ __align__(16) ushort Bs[128 * 32];

    const int t    = threadIdx.x;
    const int lane = t & 63;
    const int w    = t >> 6;
    const int wr   = w >> 1, wc = w & 1;
    const int row0 = blockIdx.y * 128;
    const int col0 = blockIdx.x * 128;

    f32x4 acc[4][4];
#pragma unroll
    for (int mi = 0; mi < 4; ++mi)
#pragma unroll
        for (int ni = 0; ni < 4; ++ni) acc[mi][ni] = (f32x4){0.f, 0.f, 0.f, 0.f};

    const int sr = t >> 2;
    const int sc = (t & 3) * 8;

    for (int k0 = 0; k0 < DM; k0 += 32) {
        gload_lds16(&A[(size_t)(row0 + sr) * DM + k0 + sc],       &As[w * 512]);
        gload_lds16(&A[(size_t)(row0 + 64 + sr) * DM + k0 + sc],  &As[2048 + w * 512]);
        gload_lds16(&Wt[(size_t)(col0 + sr) * DM + k0 + sc],      &Bs[w * 512]);
        gload_lds16(&Wt[(size_t)(col0 + 64 + sr) * DM + k0 + sc], &Bs[2048 + w * 512]);
        __syncthreads();

        bf16x8 af[4], bfr[4];
#pragma unroll
        for (int mi = 0; mi < 4; ++mi)
            af[mi] = *(const bf16x8*)&As[(wr * 64 + mi * 16 + (lane & 15)) * 32 + (lane >> 4) * 8];
#pragma unroll
        for (int ni = 0; ni < 4; ++ni)
            bfr[ni] = *(const bf16x8*)&Bs[(wc * 64 + ni * 16 + (lane & 15)) * 32 + (lane >> 4) * 8];
#pragma unroll
        for (int mi = 0; mi < 4; ++mi)
#pragma unroll
            for (int ni = 0; ni < 4; ++ni)
                acc[mi][ni] = __builtin_amdgcn_mfma_f32_16x16x32_bf16(bfr[ni], af[mi], acc[mi][ni], 0, 0, 0);
        __syncthreads();
    }

#pragma unroll
    for (int mi = 0; mi < 4; ++mi) {
        const int seq = row0 + wr * 64 + mi * 16 + (lane & 15);
#pragma unroll
        for (int ni = 0; ni < 4; ++ni) {
            const int dbase = col0 + wc * 64 + ni * 16 + (lane >> 4) * 4;
            const float4 b4 = *(const float4*)&bias[dbase];
            f32x4 o;
            o[0] = acc[mi][ni][0] + b4.x;
            o[1] = acc[mi][ni][1] + b4.y;
            o[2] = acc[mi][ni][2] + b4.z;
            o[3] = acc[mi][ni][3] + b4.w;
            *(f32x4*)&Cout[(size_t)seq * DM + dbase] = o;
        }
    }
}

// ---------------- merged K/V transpose -> fragment-linear Kf / Vt3 ----------------
// z=0: Kf[bh][kt=key/16][ks=d/32][lane][8]  (A-frag order, lane l holds
//      K[kt*16+(l&15)][ks*32+(l>>4)*8+j]).
// z=1: Vt3[bh][kc=key/32][ni=d/16][lane][8] (B-frag order, lane l holds
//      V[kc*32+(l>>4)*8+j][ni*16+(l&15)]).
__global__ __launch_bounds__(256) void transpose_kv(const ushort* __restrict__ Kh,
                                                    const ushort* __restrict__ Vh,
                                                    ushort* __restrict__ Kf,
                                                    ushort* __restrict__ Vt3) {
    __shared__ ushort tile[64][80];
    const int t    = threadIdx.x;
    const int bh   = blockIdx.x;
    const int cc   = blockIdx.y;        // 64-key group
    const int mode = blockIdx.z;        // 0 = K, 1 = V
    const int k0   = cc * 64;
    const int b    = bh >> 4;
    const int h    = bh & 15;
    const size_t panel = (size_t)b * SEQ * DM + (size_t)h * DEPTH;
    const ushort* S = mode ? Vh : Kh;

    {
        const int k = t >> 2, dc = (t & 3) * 16;
        const ushort* src = S + panel + (size_t)(k0 + k) * DM + dc;
        *(bf16x8*)&tile[k][dc]     = *(const bf16x8*)src;
        *(bf16x8*)&tile[k][dc + 8] = *(const bf16x8*)(src + 8);
    }
    __syncthreads();

    if (mode == 0) {
        const int l   = t & 63;
        const int sub = t >> 6;       // kt_local 0..3
        const int row = sub * 16 + (l & 15);
        const int db  = (l >> 4) * 8;
#pragma unroll
        for (int ks = 0; ks < 2; ++ks) {
            bf16x8 o;
#pragma unroll
            for (int j = 0; j < 8; ++j) o[j] = tile[row][ks * 32 + db + j];
            char* dst = (char*)Kf +
                        ((((size_t)bh * 128 + cc * 4 + sub) * 2) + ks) * 1024 + l * 16;
            *(bf16x8*)dst = o;
        }
    } else {
        const int l  = t & 63;
        const int ni = t >> 6;        // 0..3
        const int kr = (l >> 4) * 8;
        const int dl = ni * 16 + (l & 15);
#pragma unroll
        for (int kh = 0; kh < 2; ++kh) {
            bf16x8 o;
#pragma unroll
            for (int j = 0; j < 8; ++j) o[j] = tile[kh * 32 + kr + j][dl];
            char* dst = (char*)Vt3 +
                        (((size_t)bh * 64 + cc * 2 + kh) * 4 + ni) * 1024 + l * 16;
            *(bf16x8*)dst = o;
        }
    }
}

// ---------------- fused attention v12: frag-linear K+V, tree softmax, setprio ----------
// Structure identical to verified R18 v11; adds: pairwise-tree max/sum reductions
// (dep chain 63 -> ~6, all compile-time indices) and s_setprio(1) around MFMA clusters.
__global__ __launch_bounds__(512, 2) void attn_fused_kernel(const ushort* __restrict__ Qh,
                                                            const ushort* __restrict__ Kfrag,
                                                            const ushort* __restrict__ Vt3,
                                                            float* __restrict__ attn_out,
                                                            ushort* __restrict__ Ctx) {
    __shared__ __align__(16) ushort P_lds[16 * 2048];   // 64 KB: P tile -> partials
    __shared__ float red[256];                          // softmax stats

    const int t    = threadIdx.x;
    const int lane = t & 63;
    const int w    = t >> 6;          // 0..7
    const int qt   = blockIdx.x;      // fast axis -> panel-major dispatch
    const int bh   = blockIdx.y;
    const int b    = bh >> 4;
    const int h    = bh & 15;
    const int q0   = qt * 16;
    const int q    = lane & 15;
    const int g    = lane >> 4;       // 0..3
    const int swzP = (q & 7) << 4;

    const size_t panel = (size_t)b * SEQ * DM + (size_t)h * DEPTH;
    char* Pb = (char*)P_lds;

    const ushort* Qrow = Qh + panel + (size_t)(q0 + q) * DM + g * 8;
    const bf16x8 qf0 = *(const bf16x8*)Qrow;
    const bf16x8 qf1 = *(const bf16x8*)(Qrow + 32);

    // ---- QK^T: wave w -> kt tiles w*16 .. w*16+15, direct fragment-linear loads
    const char* Kf = (const char*)Kfrag + (size_t)bh * 262144;   // 128 kt x 2 ks x 1KB
    f32x4 acc[16];
#pragma unroll
    for (int i = 0; i < 16; ++i) acc[i] = (f32x4){0.f, 0.f, 0.f, 0.f};

    __builtin_amdgcn_s_setprio(1);
#pragma unroll
    for (int i = 0; i < 16; ++i) {
        const char* fb = Kf + (size_t)((w * 16 + i) * 2) * 1024 + lane * 16;
        const bf16x8 kf0 = *(const bf16x8*)fb;
        const bf16x8 kf1 = *(const bf16x8*)(fb + 1024);
        acc[i] = __builtin_amdgcn_mfma_f32_16x16x32_bf16(kf0, qf0, acc[i], 0, 0, 0);  // swapped
        acc[i] = __builtin_amdgcn_mfma_f32_16x16x32_bf16(kf1, qf1, acc[i], 0, 0, 0);
    }
    __builtin_amdgcn_s_setprio(0);

    // ---- softmax stats: tree reductions (compile-time indices only)
    float pm[16];
#pragma unroll
    for (int i = 0; i < 16; ++i)
        pm[i] = fmaxf(fmaxf(acc[i][0], acc[i][1]), fmaxf(acc[i][2], acc[i][3]));
#pragma unroll
    for (int s = 8; s > 0; s >>= 1)
#pragma unroll
        for (int i = 0; i < s; ++i) pm[i] = fmaxf(pm[i], pm[i + s]);
    float mm = pm[0];
    mm = fmaxf(mm, __shfl_xor(mm, 16));
    mm = fmaxf(mm, __shfl_xor(mm, 32));
    if (lane < 16) red[w * 16 + lane] = mm;
    __syncthreads();

    float mx = red[q];
#pragma unroll
    for (int ww = 1; ww < 8; ++ww) mx = fmaxf(mx, red[ww * 16 + q]);

    float ps[16];
#pragma unroll
    for (int i = 0; i < 16; ++i) {
        const float e0 = __expf(acc[i][0] - mx);
        const float e1 = __expf(acc[i][1] - mx);
        const float e2 = __expf(acc[i][2] - mx);
        const float e3 = __expf(acc[i][3] - mx);
        acc[i][0] = e0; acc[i][1] = e1; acc[i][2] = e2; acc[i][3] = e3;
        ps[i] = (e0 + e1) + (e2 + e3);
    }
#pragma unroll
    for (int s = 8; s > 0; s >>= 1)
#pragma unroll
        for (int i = 0; i < s; ++i) ps[i] += ps[i + s];
    float ssum = ps[0];
    ssum += __shfl_xor(ssum, 16);
    ssum += __shfl_xor(ssum, 32);
    if (lane < 16) red[128 + w * 16 + lane] = ssum;
    __syncthreads();

    float tot = red[128 + q];
#pragma unroll
    for (int ww = 1; ww < 8; ++ww) tot += red[128 + ww * 16 + q];
    const float rinv = 1.f / tot;

    // ---- pack normalized P (bf16, swizzled): key w*256 + i*16 + g*4 + r (R11-verified)
#pragma unroll
    for (int i = 0; i < 16; ++i) {
        const float p0 = acc[i][0] * rinv;
        const float p1 = acc[i][1] * rinv;
        const float p2 = acc[i][2] * rinv;
        const float p3 = acc[i][3] * rinv;
        uint2 uu;
        uu.x = (uint)f2b(p0) | ((uint)f2b(p1) << 16);
        uu.y = (uint)f2b(p2) | ((uint)f2b(p3) << 16);
        *(uint2*)(Pb + q * 4096 + ((w * 512 + i * 32 + g * 8) ^ swzP)) = uu;
    }
    __syncthreads();

    // ---- attn store: wave w writes rows 0..15, cols [w*256,+256); 1KB/inst, NT
    float* attn_base = attn_out + ((size_t)bh * SEQ + q0) * SEQ;
#pragma unroll
    for (int it = 0; it < 16; ++it) {
        const int bofs = (w * 512 + lane * 8) ^ ((it & 7) << 4);
        const ushort4 p4 = *(const ushort4*)(Pb + it * 4096 + bofs);
        f32x4 o;
        o[0] = b2f(p4.x); o[1] = b2f(p4.y); o[2] = b2f(p4.z); o[3] = b2f(p4.w);
        __builtin_nontemporal_store(o, (f32x4*)&attn_base[(size_t)it * SEQ + w * 256 + lane * 4]);
    }

    // ---- PV: wave w over keys {w*256 + s8*32 .. +32}; V fragment-linear (verified R16)
    const char* Vf = (const char*)Vt3 + (size_t)bh * 262144;   // 64 kc x 4 ni x 1KB
    f32x4 ctx[4];
#pragma unroll
    for (int ni = 0; ni < 4; ++ni) ctx[ni] = (f32x4){0.f, 0.f, 0.f, 0.f};

    __builtin_amdgcn_s_setprio(1);
#pragma unroll
    for (int s8 = 0; s8 < 8; ++s8) {
        const bf16x8 af = *(const bf16x8*)(Pb + q * 4096 + ((w * 512 + s8 * 64 + g * 16) ^ swzP));
        const char* fb = Vf + (size_t)((w * 8 + s8) * 4) * 1024 + lane * 16;
#pragma unroll
        for (int ni = 0; ni < 4; ++ni) {
            const bf16x8 bfr = *(const bf16x8*)(fb + ni * 1024);
            ctx[ni] = __builtin_amdgcn_mfma_f32_16x16x32_bf16(af, bfr, ctx[ni], 0, 0, 0);
        }
    }
    __builtin_amdgcn_s_setprio(0);
    __syncthreads();   // all P reads done; reuse P_lds as f32 partials [8][16][64]

    float* part = (float*)P_lds;
#pragma unroll
    for (int ni = 0; ni < 4; ++ni) {
#pragma unroll
        for (int r = 0; r < 4; ++r) {
            part[(w * 16 + g * 4 + r) * 64 + ni * 16 + q] = ctx[ni][r];
        }
    }
    __syncthreads();

#pragma unroll
    for (int idx = t; idx < 1024; idx += 512) {
        const int qq = idx >> 6, d = idx & 63;
        float s2 = 0.f;
#pragma unroll
        for (int ww = 0; ww < 8; ++ww) s2 += part[ww * 1024 + idx];
        Ctx[(size_t)(b * SEQ + q0 + qq) * DM + h * DEPTH + d] = f2b(s2);
    }
}

extern "C" void kernel_launch(void* const* d_in, const int* in_sizes, int n_in,
                              void* d_out, int out_size, void* d_ws, size_t ws_size,
                              hipStream_t stream) {
    const float* x  = (const float*)d_in[0];
    const float* wq = (const float*)d_in[1];
    const float* bq = (const float*)d_in[2];
    const float* wk = (const float*)d_in[3];
    const float* bk = (const float*)d_in[4];
    const float* wv = (const float*)d_in[5];
    const float* bv = (const float*)d_in[6];
    const float* wo = (const float*)d_in[7];
    const float* bo = (const float*)d_in[8];

    float* out  = (float*)d_out;                          // [2,2048,1024]
    float* attn = out + (size_t)MROWS * DM;               // [2,16,2048,2048] fp32

    ushort* ws  = (ushort*)d_ws;
    ushort* xb  = ws;                        // 4096x1024 bf16
    ushort* wqt = xb + (size_t)MROWS * DM;   // [wqt|wkt|wvt|wot] contiguous, each 1024x1024
    ushort* wot = wqt + (size_t)3 * DM * DM;
    ushort* Qh  = wot + (size_t)DM * DM;     // [Qh|Kh|Vh] contiguous, each 4096x1024 bf16
    ushort* Kh  = Qh + (size_t)MROWS * DM;
    ushort* Vh  = Kh + (size_t)MROWS * DM;
    ushort* cxb = Vh + (size_t)MROWS * DM;
    ushort* Vt3 = cxb + (size_t)MROWS * DM;  // [32 bh][64 kc][4 ni][64 lane][8] bf16, 8MB
    ushort* Kf  = Vt3 + (size_t)BATCH * NH * DEPTH * SEQ;  // [32 bh][128 kt][2 ks][64][8], 8MB

    convert_f32_bf16<<<dim3(MROWS * DM / 4 / 256), 256, 0, stream>>>(x, xb, MROWS * DM / 4);
    transpose_convert4<<<dim3(DM / 32, DM / 32, 4), 256, 0, stream>>>(wq, wk, wv, wo, wqt);

    gemm_qkv_mfma<<<dim3(3 * DM / 128, MROWS / 128), 256, 0, stream>>>(xb, wqt, bq, bk, bv, Qh);

    transpose_kv<<<dim3(BATCH * NH, SEQ / 64, 2), 256, 0, stream>>>(Kh, Vh, Kf, Vt3);

    attn_fused_kernel<<<dim3(SEQ / 16, BATCH * NH), 512, 0, stream>>>(Qh, Kf, Vt3, attn, cxb);

    gemm_mfma_f32<<<dim3(DM / 128, MROWS / 128), 256, 0, stream>>>(cxb, wot, bo, out);
}

// Round 20
// 219.673 us; speedup vs baseline: 1.0523x; 1.0523x over previous
//
#include <hip/hip_runtime.h>
#include <hip/hip_bf16.h>

#define SEQ 2048
#define BATCH 2
#define NH 16
#define DM 1024
#define DEPTH 64
#define MROWS (BATCH * SEQ)   // 4096

typedef __attribute__((ext_vector_type(8))) short bf16x8;
typedef __attribute__((ext_vector_type(4))) float f32x4;

__device__ __forceinline__ float b2f(ushort u) {
    union { uint i; float f; } v; v.i = ((uint)u) << 16; return v.f;
}
__device__ __forceinline__ ushort f2b(float f) {
    __hip_bfloat16 h = __float2bfloat16(f);
    return *reinterpret_cast<ushort*>(&h);
}

__device__ __forceinline__ void gload_lds16(const void* g, void* l) {
    __builtin_amdgcn_global_load_lds((const __attribute__((address_space(1))) void*)g,
                                     (__attribute__((address_space(3))) void*)l, 16, 0, 0);
}

// ---------------- fp32 -> bf16 elementwise ----------------
__global__ __launch_bounds__(256) void convert_f32_bf16(const float* __restrict__ in,
                                                        ushort* __restrict__ outp, int n4) {
    int i = blockIdx.x * 256 + threadIdx.x;
    if (i < n4) {
        const float4 v = ((const float4*)in)[i];
        ushort4 o;
        o.x = f2b(v.x); o.y = f2b(v.y); o.z = f2b(v.z); o.w = f2b(v.w);
        ((ushort4*)outp)[i] = o;
    }
}

// ---------------- 4x fused: fp32 W[K][N] -> bf16 Wt[N][K], z selects weight ----------------
__global__ __launch_bounds__(256) void transpose_convert4(const float* __restrict__ w0,
                                                          const float* __restrict__ w1,
                                                          const float* __restrict__ w2,
                                                          const float* __restrict__ w3,
                                                          ushort* __restrict__ WtBase) {
    __shared__ float tile[32][33];
    const int z = blockIdx.z;
    const float* W = (z == 0) ? w0 : (z == 1) ? w1 : (z == 2) ? w2 : w3;
    ushort* Wt = WtBase + (size_t)z * DM * DM;
    const int bx = blockIdx.x * 32;  // n base
    const int by = blockIdx.y * 32;  // k base
    const int tx = threadIdx.x & 31, ty = threadIdx.x >> 5;
#pragma unroll
    for (int i = 0; i < 32; i += 8)
        tile[ty + i][tx] = W[(size_t)(by + ty + i) * DM + bx + tx];
    __syncthreads();
#pragma unroll
    for (int i = 0; i < 32; i += 8)
        Wt[(size_t)(bx + ty + i) * DM + by + tx] = f2b(tile[tx][ty + i]);
}

// ---------------- fused QKV GEMM: [4096,1024] @ [1024,3072] + bias -> bf16 ----------------
// Q bank (bank==0) is pre-scaled by 1/sqrt(DEPTH)=0.125 so attn skips the logit scale.
__global__ __launch_bounds__(256) void gemm_qkv_mfma(const ushort* __restrict__ A,
                                                     const ushort* __restrict__ WtAll,
                                                     const float* __restrict__ bq,
                                                     const float* __restrict__ bk,
                                                     const float* __restrict__ bv,
                                                     ushort* __restrict__ OutBase) {
    __shared__ __align__(16) ushort As[128 * 32];
    __shared__ __align__(16) ushort Bs[128 * 32];

    const int t    = threadIdx.x;
    const int lane = t & 63;
    const int w    = t >> 6;
    const int wr   = w >> 1, wc = w & 1;
    const int row0 = blockIdx.y * 128;
    const int col0 = blockIdx.x * 128;           // 0..2944
    const int bank = col0 >> 10;                 // 0,1,2
    const float* bias = (bank == 0) ? bq : (bank == 1) ? bk : bv;
    const float scale = (bank == 0) ? 0.125f : 1.0f;
    const int ccol0 = col0 & 1023;
    ushort* Cout = OutBase + (size_t)bank * MROWS * DM;

    f32x4 acc[4][4];
#pragma unroll
    for (int mi = 0; mi < 4; ++mi)
#pragma unroll
        for (int ni = 0; ni < 4; ++ni) acc[mi][ni] = (f32x4){0.f, 0.f, 0.f, 0.f};

    const int sr = t >> 2;
    const int sc = (t & 3) * 8;

    for (int k0 = 0; k0 < DM; k0 += 32) {
        gload_lds16(&A[(size_t)(row0 + sr) * DM + k0 + sc],          &As[w * 512]);
        gload_lds16(&A[(size_t)(row0 + 64 + sr) * DM + k0 + sc],     &As[2048 + w * 512]);
        gload_lds16(&WtAll[(size_t)(col0 + sr) * DM + k0 + sc],      &Bs[w * 512]);
        gload_lds16(&WtAll[(size_t)(col0 + 64 + sr) * DM + k0 + sc], &Bs[2048 + w * 512]);
        __syncthreads();

        bf16x8 af[4], bfr[4];
#pragma unroll
        for (int mi = 0; mi < 4; ++mi)
            af[mi] = *(const bf16x8*)&As[(wr * 64 + mi * 16 + (lane & 15)) * 32 + (lane >> 4) * 8];
#pragma unroll
        for (int ni = 0; ni < 4; ++ni)
            bfr[ni] = *(const bf16x8*)&Bs[(wc * 64 + ni * 16 + (lane & 15)) * 32 + (lane >> 4) * 8];
#pragma unroll
        for (int mi = 0; mi < 4; ++mi)
#pragma unroll
            for (int ni = 0; ni < 4; ++ni)
                acc[mi][ni] = __builtin_amdgcn_mfma_f32_16x16x32_bf16(af[mi], bfr[ni], acc[mi][ni], 0, 0, 0);
        __syncthreads();
    }

    float bb[4];
#pragma unroll
    for (int ni = 0; ni < 4; ++ni) bb[ni] = bias[ccol0 + wc * 64 + ni * 16 + (lane & 15)];

#pragma unroll
    for (int mi = 0; mi < 4; ++mi) {
        const int row = row0 + wr * 64 + mi * 16 + (lane >> 4) * 4;
#pragma unroll
        for (int ni = 0; ni < 4; ++ni) {
            const int col = ccol0 + wc * 64 + ni * 16 + (lane & 15);
#pragma unroll
            for (int r = 0; r < 4; ++r)
                Cout[(size_t)(row + r) * DM + col] = f2b((acc[mi][ni][r] + bb[ni]) * scale);
        }
    }
}

// ---------------- bf16 MFMA GEMM: C = A @ Wt^T + bias, fp32 out ----------------
__global__ __launch_bounds__(256) void gemm_mfma_f32(const ushort* __restrict__ A,
                                                     const ushort* __restrict__ Wt,
                                                     const float* __restrict__ bias,
                                                     float* __restrict__ Cout) {
    __shared__ __align__(16) ushort As[128 * 32];
    __shared__ __align__(16) ushort Bs[128 * 32];

    const int t    = threadIdx.x;
    const int lane = t & 63;
    const int w    = t >> 6;
    const int wr   = w >> 1, wc = w & 1;
    const int row0 = blockIdx.y * 128;
    const int col0 = blockIdx.x * 128;

    f32x4 acc[4][4];
#pragma unroll
    for (int mi = 0; mi < 4; ++mi)
#pragma unroll
        for (int ni = 0; ni < 4; ++ni) acc[mi][ni] = (f32x4){0.f, 0.f, 0.f, 0.f};

    const int sr = t >> 2;
    const int sc = (t & 3) * 8;

    for (int k0 = 0; k0 < DM; k0 += 32) {
        gload_lds16(&A[(size_t)(row0 + sr) * DM + k0 + sc],       &As[w * 512]);
        gload_lds16(&A[(size_t)(row0 + 64 + sr) * DM + k0 + sc],  &As[2048 + w * 512]);
        gload_lds16(&Wt[(size_t)(col0 + sr) * DM + k0 + sc],      &Bs[w * 512]);
        gload_lds16(&Wt[(size_t)(col0 + 64 + sr) * DM + k0 + sc], &Bs[2048 + w * 512]);
        __syncthreads();

        bf16x8 af[4], bfr[4];
#pragma unroll
        for (int mi = 0; mi < 4; ++mi)
            af[mi] = *(const bf16x8*)&As[(wr * 64 + mi * 16 + (lane & 15)) * 32 + (lane >> 4) * 8];
#pragma unroll
        for (int ni = 0; ni < 4; ++ni)
            bfr[ni] = *(const bf16x8*)&Bs[(wc * 64 + ni * 16 + (lane & 15)) * 32 + (lane >> 4) * 8];
#pragma unroll
        for (int mi = 0; mi < 4; ++mi)
#pragma unroll
            for (int ni = 0; ni < 4; ++ni)
                acc[mi][ni] = __builtin_amdgcn_mfma_f32_16x16x32_bf16(af[mi], bfr[ni], acc[mi][ni], 0, 0, 0);
        __syncthreads();
    }

    float bb[4];
#pragma unroll
    for (int ni = 0; ni < 4; ++ni) bb[ni] = bias[col0 + wc * 64 + ni * 16 + (lane & 15)];

#pragma unroll
    for (int mi = 0; mi < 4; ++mi) {
        const int row = row0 + wr * 64 + mi * 16 + (lane >> 4) * 4;
#pragma unroll
        for (int ni = 0; ni < 4; ++ni) {
            const int col = col0 + wc * 64 + ni * 16 + (lane & 15);
#pragma unroll
            for (int r = 0; r < 4; ++r)
                Cout[(size_t)(row + r) * DM + col] = acc[mi][ni][r] + bb[ni];
        }
    }
}

// ---------------- V transpose -> fragment-linear Vt3 (verified R16) ----------------
// Vt3[bh][kc=key/32][ni=d/16][lane][8] bf16: exact MFMA B-fragment order.
__global__ __launch_bounds__(256) void transpose_v(const ushort* __restrict__ Vh,
                                                   ushort* __restrict__ Vt3) {
    __shared__ ushort tile[64][80];
    const int t  = threadIdx.x;
    const int bh = blockIdx.x;
    const int cc = blockIdx.y;        // 64-key group
    const int k0 = cc * 64;
    const int b  = bh >> 4;
    const int h  = bh & 15;
    const size_t panel = (size_t)b * SEQ * DM + (size_t)h * DEPTH;

    {
        const int k = t >> 2, dc = (t & 3) * 16;
        const ushort* src = Vh + panel + (size_t)(k0 + k) * DM + dc;
        *(bf16x8*)&tile[k][dc]     = *(const bf16x8*)src;
        *(bf16x8*)&tile[k][dc + 8] = *(const bf16x8*)(src + 8);
    }
    __syncthreads();
    {
        const int l  = t & 63;
        const int ni = t >> 6;        // 0..3
        const int kr = (l >> 4) * 8;
        const int dl = ni * 16 + (l & 15);
#pragma unroll
        for (int kh = 0; kh < 2; ++kh) {
            bf16x8 o;
#pragma unroll
            for (int j = 0; j < 8; ++j) o[j] = tile[kh * 32 + kr + j][dl];
            char* dst = (char*)Vt3 +
                        (((size_t)bh * 64 + cc * 2 + kh) * 4 + ni) * 1024 + l * 16;
            *(bf16x8*)dst = o;
        }
    }
}

// ---------------- K transpose -> fragment-linear Kf ----------------
// Kf[bh][kt=key/16][ks=d/32][lane][8] bf16: exact MFMA A-fragment order (verified map:
// lane l holds K[kt*16 + (l&15)][ks*32 + (l>>4)*8 + j]). QK loads become 1KB contiguous.
__global__ __launch_bounds__(256) void transpose_k(const ushort* __restrict__ Kh,
                                                   ushort* __restrict__ Kf) {
    __shared__ ushort tile[64][80];
    const int t  = threadIdx.x;
    const int bh = blockIdx.x;
    const int cc = blockIdx.y;        // 64-key group
    const int k0 = cc * 64;
    const int b  = bh >> 4;
    const int h  = bh & 15;
    const size_t panel = (size_t)b * SEQ * DM + (size_t)h * DEPTH;

    {
        const int k = t >> 2, dc = (t & 3) * 16;
        const ushort* src = Kh + panel + (size_t)(k0 + k) * DM + dc;
        *(bf16x8*)&tile[k][dc]     = *(const bf16x8*)src;
        *(bf16x8*)&tile[k][dc + 8] = *(const bf16x8*)(src + 8);
    }
    __syncthreads();
    {
        const int l   = t & 63;
        const int sub = t >> 6;       // kt_local 0..3
        const int row = sub * 16 + (l & 15);
        const int db  = (l >> 4) * 8;
#pragma unroll
        for (int ks = 0; ks < 2; ++ks) {
            bf16x8 o;
#pragma unroll
            for (int j = 0; j < 8; ++j) o[j] = tile[row][ks * 32 + db + j];
            char* dst = (char*)Kf +
                        ((((size_t)bh * 128 + cc * 4 + sub) * 2) + ks) * 1024 + l * 16;
            *(bf16x8*)dst = o;
        }
    }
}

// ---------------- fused attention v11: fragment-linear K AND V (zero-staging QK+PV) --------
// 512 threads (8 waves), one (b,h) x 16 q-rows. Wave w owns keys [w*256, w*256+256)
// (R11-verified ownership/pack/PV offsets). QK: 16 barrier-free iters of
// {2 x 1KB contiguous Kf loads + 2 MFMA}. PV: same pattern on Vt3 (verified R16).
// Only ~6 block barriers total (softmax stats + pack + reduce).
__global__ __launch_bounds__(512, 2) void attn_fused_kernel(const ushort* __restrict__ Qh,
                                                            const ushort* __restrict__ Kfrag,
                                                            const ushort* __restrict__ Vt3,
                                                            float* __restrict__ attn_out,
                                                            ushort* __restrict__ Ctx) {
    __shared__ __align__(16) ushort P_lds[16 * 2048];   // 64 KB: P tile -> partials
    __shared__ float red[256];                          // softmax stats

    const int t    = threadIdx.x;
    const int lane = t & 63;
    const int w    = t >> 6;          // 0..7
    const int qt   = blockIdx.x;      // fast axis -> panel-major dispatch
    const int bh   = blockIdx.y;
    const int b    = bh >> 4;
    const int h    = bh & 15;
    const int q0   = qt * 16;
    const int q    = lane & 15;
    const int g    = lane >> 4;       // 0..3
    const int swzP = (q & 7) << 4;

    const size_t panel = (size_t)b * SEQ * DM + (size_t)h * DEPTH;
    char* Pb = (char*)P_lds;

    const ushort* Qrow = Qh + panel + (size_t)(q0 + q) * DM + g * 8;
    const bf16x8 qf0 = *(const bf16x8*)Qrow;
    const bf16x8 qf1 = *(const bf16x8*)(Qrow + 32);

    // ---- QK^T: wave w -> kt tiles w*16 .. w*16+15, direct fragment-linear loads
    const char* Kf = (const char*)Kfrag + (size_t)bh * 262144;   // 128 kt x 2 ks x 1KB
    f32x4 acc[16];
#pragma unroll
    for (int i = 0; i < 16; ++i) acc[i] = (f32x4){0.f, 0.f, 0.f, 0.f};

#pragma unroll
    for (int i = 0; i < 16; ++i) {
        const char* fb = Kf + (size_t)((w * 16 + i) * 2) * 1024 + lane * 16;
        const bf16x8 kf0 = *(const bf16x8*)fb;
        const bf16x8 kf1 = *(const bf16x8*)(fb + 1024);
        acc[i] = __builtin_amdgcn_mfma_f32_16x16x32_bf16(kf0, qf0, acc[i], 0, 0, 0);  // swapped
        acc[i] = __builtin_amdgcn_mfma_f32_16x16x32_bf16(kf1, qf1, acc[i], 0, 0, 0);
    }

    // ---- softmax stats: lane-local -> lanes {q,q+16,q+32,q+48} -> waves
    float mm = acc[0][0];
#pragma unroll
    for (int i = 0; i < 16; ++i) {
#pragma unroll
        for (int r = 0; r < 4; ++r) mm = fmaxf(mm, acc[i][r]);
    }
    mm = fmaxf(mm, __shfl_xor(mm, 16));
    mm = fmaxf(mm, __shfl_xor(mm, 32));
    if (lane < 16) red[w * 16 + lane] = mm;
    __syncthreads();

    float mx = red[q];
#pragma unroll
    for (int ww = 1; ww < 8; ++ww) mx = fmaxf(mx, red[ww * 16 + q]);

    float ssum = 0.f;
#pragma unroll
    for (int i = 0; i < 16; ++i) {
#pragma unroll
        for (int r = 0; r < 4; ++r) {
            const float p = __expf(acc[i][r] - mx);
            acc[i][r] = p;
            ssum += p;
        }
    }
    ssum += __shfl_xor(ssum, 16);
    ssum += __shfl_xor(ssum, 32);
    if (lane < 16) red[128 + w * 16 + lane] = ssum;
    __syncthreads();

    float tot = red[128 + q];
#pragma unroll
    for (int ww = 1; ww < 8; ++ww) tot += red[128 + ww * 16 + q];
    const float rinv = 1.f / tot;

    // ---- pack normalized P (bf16, swizzled): key w*256 + i*16 + g*4 + r (R11-verified)
#pragma unroll
    for (int i = 0; i < 16; ++i) {
        const float p0 = acc[i][0] * rinv;
        const float p1 = acc[i][1] * rinv;
        const float p2 = acc[i][2] * rinv;
        const float p3 = acc[i][3] * rinv;
        uint2 uu;
        uu.x = (uint)f2b(p0) | ((uint)f2b(p1) << 16);
        uu.y = (uint)f2b(p2) | ((uint)f2b(p3) << 16);
        *(uint2*)(Pb + q * 4096 + ((w * 512 + i * 32 + g * 8) ^ swzP)) = uu;
    }
    __syncthreads();

    // ---- attn store: wave w writes rows 0..15, cols [w*256,+256); 1KB/inst, NT
    float* attn_base = attn_out + ((size_t)bh * SEQ + q0) * SEQ;
#pragma unroll
    for (int it = 0; it < 16; ++it) {
        const int bofs = (w * 512 + lane * 8) ^ ((it & 7) << 4);
        const ushort4 p4 = *(const ushort4*)(Pb + it * 4096 + bofs);
        f32x4 o;
        o[0] = b2f(p4.x); o[1] = b2f(p4.y); o[2] = b2f(p4.z); o[3] = b2f(p4.w);
        __builtin_nontemporal_store(o, (f32x4*)&attn_base[(size_t)it * SEQ + w * 256 + lane * 4]);
    }

    // ---- PV: wave w over keys {w*256 + s8*32 .. +32}; V fragment-linear (verified R16)
    const char* Vf = (const char*)Vt3 + (size_t)bh * 262144;   // 64 kc x 4 ni x 1KB
    f32x4 ctx[4];
#pragma unroll
    for (int ni = 0; ni < 4; ++ni) ctx[ni] = (f32x4){0.f, 0.f, 0.f, 0.f};

#pragma unroll
    for (int s8 = 0; s8 < 8; ++s8) {
        const bf16x8 af = *(const bf16x8*)(Pb + q * 4096 + ((w * 512 + s8 * 64 + g * 16) ^ swzP));
        const char* fb = Vf + (size_t)((w * 8 + s8) * 4) * 1024 + lane * 16;
#pragma unroll
        for (int ni = 0; ni < 4; ++ni) {
            const bf16x8 bfr = *(const bf16x8*)(fb + ni * 1024);
            ctx[ni] = __builtin_amdgcn_mfma_f32_16x16x32_bf16(af, bfr, ctx[ni], 0, 0, 0);
        }
    }
    __syncthreads();   // all P reads done; reuse P_lds as f32 partials [8][16][64]

    float* part = (float*)P_lds;
#pragma unroll
    for (int ni = 0; ni < 4; ++ni) {
#pragma unroll
        for (int r = 0; r < 4; ++r) {
            part[(w * 16 + g * 4 + r) * 64 + ni * 16 + q] = ctx[ni][r];
        }
    }
    __syncthreads();

#pragma unroll
    for (int idx = t; idx < 1024; idx += 512) {
        const int qq = idx >> 6, d = idx & 63;
        float s2 = 0.f;
#pragma unroll
        for (int ww = 0; ww < 8; ++ww) s2 += part[ww * 1024 + idx];
        Ctx[(size_t)(b * SEQ + q0 + qq) * DM + h * DEPTH + d] = f2b(s2);
    }
}

extern "C" void kernel_launch(void* const* d_in, const int* in_sizes, int n_in,
                              void* d_out, int out_size, void* d_ws, size_t ws_size,
                              hipStream_t stream) {
    const float* x  = (const float*)d_in[0];
    const float* wq = (const float*)d_in[1];
    const float* bq = (const float*)d_in[2];
    const float* wk = (const float*)d_in[3];
    const float* bk = (const float*)d_in[4];
    const float* wv = (const float*)d_in[5];
    const float* bv = (const float*)d_in[6];
    const float* wo = (const float*)d_in[7];
    const float* bo = (const float*)d_in[8];

    float* out  = (float*)d_out;                          // [2,2048,1024]
    float* attn = out + (size_t)MROWS * DM;               // [2,16,2048,2048] fp32

    ushort* ws  = (ushort*)d_ws;
    ushort* xb  = ws;                        // 4096x1024 bf16
    ushort* wqt = xb + (size_t)MROWS * DM;   // [wqt|wkt|wvt|wot] contiguous, each 1024x1024
    ushort* wot = wqt + (size_t)3 * DM * DM;
    ushort* Qh  = wot + (size_t)DM * DM;     // [Qh|Kh|Vh] contiguous, each 4096x1024 bf16
    ushort* Kh  = Qh + (size_t)MROWS * DM;
    ushort* Vh  = Kh + (size_t)MROWS * DM;
    ushort* cxb = Vh + (size_t)MROWS * DM;
    ushort* Vt3 = cxb + (size_t)MROWS * DM;  // [32 bh][64 kc][4 ni][64 lane][8] bf16, 8MB
    ushort* Kf  = Vt3 + (size_t)BATCH * NH * DEPTH * SEQ;  // [32 bh][128 kt][2 ks][64][8], 8MB

    convert_f32_bf16<<<dim3(MROWS * DM / 4 / 256), 256, 0, stream>>>(x, xb, MROWS * DM / 4);
    transpose_convert4<<<dim3(DM / 32, DM / 32, 4), 256, 0, stream>>>(wq, wk, wv, wo, wqt);

    gemm_qkv_mfma<<<dim3(3 * DM / 128, MROWS / 128), 256, 0, stream>>>(xb, wqt, bq, bk, bv, Qh);

    transpose_v<<<dim3(BATCH * NH, SEQ / 64), 256, 0, stream>>>(Vh, Vt3);
    transpose_k<<<dim3(BATCH * NH, SEQ / 64), 256, 0, stream>>>(Kh, Kf);

    attn_fused_kernel<<<dim3(SEQ / 16, BATCH * NH), 512, 0, stream>>>(Qh, Kf, Vt3, attn, cxb);

    gemm_mfma_f32<<<dim3(DM / 128, MROWS / 128), 256, 0, stream>>>(cxb, wot, bo, out);
}